// Round 8
// baseline (129.525 us; speedup 1.0000x reference)
//
#include <hip/hip_runtime.h>

// Problem constants (B=8, K=8192 from setup_inputs).
#define KPTS 8192
#define BATCH 8
#define TPB 256

#define S_SPLIT 8                      // n-splits per batch
#define NR (KPTS / S_SPLIT)            // 1024 n per block
#define CH 512                         // ori points staged per LDS chunk
#define NCHUNK (NR / CH)               // 2
#define MW 8                           // m-tiles (16 rows) per wave
#define WAVES 4
#define MBLOCK (16 * MW * WAVES)       // 512 m per block
#define MBLK (KPTS / MBLOCK)           // 16 m-blocks per batch
#define GRID_A (BATCH * MBLK * S_SPLIT)   // 1024 blocks

#define SB 32
#define GRID_B (BATCH * SB)            // 256 blocks

typedef short v8s __attribute__((ext_vector_type(8)));
typedef float v4f __attribute__((ext_vector_type(4)));

// Device-global scratch: fully overwritten before read every call =>
// no init pass, graph-replay idempotent, d_ws poison irrelevant.
__device__ float g_ws[(size_t)BATCH * S_SPLIT * KPTS];   // 2 MB partial mins
__device__ float g_partial[GRID_B];

__device__ __forceinline__ unsigned short f2bf(float x) {   // RNE truncate
    unsigned u = __float_as_uint(x);
    u += 0x7FFF + ((u >> 16) & 1);
    return (unsigned short)(u >> 16);
}
__device__ __forceinline__ float bf2f(unsigned short h) {
    return __uint_as_float(((unsigned)h) << 16);
}
#define ONE_BF ((short)0x3F80)

// K-slot packing (K=13 of 32; quads 2,3 all-zero):
//  k0-2 : (-2a)_hi . o_hi     k3-5 : (-2a)_hi . o_lo
//  k6-8 : (-2a)_lo . o_hi     k9,10: 1 * oo_hi/lo     k11,12: aa_hi/lo * 1
// => D[m][n] = -2 a.o + |o|^2 + |a|^2  (full distance, error ~4e-4)
__global__ __launch_bounds__(TPB) void phaseA(const float* __restrict__ adv,
                                              const float* __restrict__ ori) {
    __shared__ short sB[CH * 16];   // per ori point: 16 bf16 (q0 row | q1 row)

    const int blk = blockIdx.x;
    const int b   = blk >> 7;                    // / (MBLK*S_SPLIT)
    const int mb  = (blk >> 3) & (MBLK - 1);
    const int s   = blk & (S_SPLIT - 1);
    const int tid = threadIdx.x;
    const int wave = tid >> 6, lane = tid & 63;
    const int quad = lane >> 4, col = lane & 15;

    // ---- A fragments (adv): built once per wave, reused for all n ----
    // A-operand layout: A[m = lane&15][k = quad*8 + j]
    const int m_wave = mb * MBLOCK + wave * (MW * 16);
    v8s af[MW];
    float mn[MW][4];
#pragma unroll
    for (int t = 0; t < MW; ++t) {
        const float* apt = adv + ((size_t)b * KPTS + m_wave + t * 16 + col) * 3;
        float ax = apt[0], ay = apt[1], az = apt[2];
        float sx = -2.f * ax, sy = -2.f * ay, sz = -2.f * az;
        unsigned short shx = f2bf(sx), shy = f2bf(sy), shz = f2bf(sz);
        unsigned short slx = f2bf(sx - bf2f(shx)), sly = f2bf(sy - bf2f(shy)),
                       slz = f2bf(sz - bf2f(shz));
        float aa = ax * ax + ay * ay + az * az;
        unsigned short aah = f2bf(aa), aal = f2bf(aa - bf2f(aah));
        v8s q0 = { (short)shx, (short)shy, (short)shz,
                   (short)shx, (short)shy, (short)shz, (short)slx, (short)sly };
        v8s q1 = { (short)slz, ONE_BF, ONE_BF, (short)aah, (short)aal, 0, 0, 0 };
        af[t] = quad == 0 ? q0 : (quad == 1 ? q1 : (v8s)0);
        mn[t][0] = mn[t][1] = mn[t][2] = mn[t][3] = __builtin_huge_valf();
    }

    const int n_base = s * NR;
    for (int ch = 0; ch < NCHUNK; ++ch) {
        __syncthreads();
        // ---- stage CH ori points as pre-packed B-fragment rows ----
#pragma unroll
        for (int pp = 0; pp < 2; ++pp) {
            int p = tid * 2 + pp;
            const float* opt = ori + ((size_t)b * KPTS + n_base + ch * CH + p) * 3;
            float ox = opt[0], oy = opt[1], oz = opt[2];
            unsigned short ohx = f2bf(ox), ohy = f2bf(oy), ohz = f2bf(oz);
            unsigned short olx = f2bf(ox - bf2f(ohx)), oly = f2bf(oy - bf2f(ohy)),
                           olz = f2bf(oz - bf2f(ohz));
            float oo = ox * ox + oy * oy + oz * oz;
            unsigned short ooh = f2bf(oo), ool = f2bf(oo - bf2f(ooh));
            v8s r0 = { (short)ohx, (short)ohy, (short)ohz,
                       (short)olx, (short)oly, (short)olz, (short)ohx, (short)ohy };
            v8s r1 = { (short)ohz, (short)ooh, (short)ool, ONE_BF, ONE_BF, 0, 0, 0 };
            ((v8s*)sB)[p * 2 + 0] = r0;
            ((v8s*)sB)[p * 2 + 1] = r1;
        }
        __syncthreads();

        // ---- consume: 16-col n-tiles; epilogue = 4 v_min per MFMA tile ----
        for (int nb = 0; nb < CH / 16; ++nb) {
            v8s bq = (v8s)0;                      // quads 2,3 contribute zeros
            if (quad < 2)
                bq = *(const v8s*)&sB[(nb * 16 + col) * 16 + quad * 8];
#pragma unroll
            for (int t = 0; t < MW; ++t) {
                v4f d = __builtin_amdgcn_mfma_f32_16x16x32_bf16(
                            af[t], bq, (v4f){0.f, 0.f, 0.f, 0.f}, 0, 0, 0);
                mn[t][0] = fminf(mn[t][0], d[0]);
                mn[t][1] = fminf(mn[t][1], d[1]);
                mn[t][2] = fminf(mn[t][2], d[2]);
                mn[t][3] = fminf(mn[t][3], d[3]);
            }
        }
    }

    // D layout: col = lane&15 (n-class), row m = quad*4 + reg. Min over the
    // 16 n-classes = butterfly over the quad's 16 lanes, then col==0 stores.
#pragma unroll
    for (int t = 0; t < MW; ++t)
#pragma unroll
        for (int r = 0; r < 4; ++r) {
            float v = mn[t][r];
#pragma unroll
            for (int off = 1; off <= 8; off <<= 1)
                v = fminf(v, __shfl_xor(v, off, 64));
            mn[t][r] = v;
        }
    if (col == 0) {
        float* dst = g_ws + ((size_t)(b * S_SPLIT + s)) * KPTS + m_wave;
#pragma unroll
        for (int t = 0; t < MW; ++t)
#pragma unroll
            for (int r = 0; r < 4; ++r)
                dst[t * 16 + quad * 4 + r] = mn[t][r];
    }
}

// ---- phaseB: min over S_SPLIT slices, block max-reduce -> g_partial ------
__global__ __launch_bounds__(TPB) void phaseB() {
    const int blk = blockIdx.x;              // GRID_B = BATCH * SB
    const int b   = blk / SB;
    const int sb  = blk % SB;
    const int tid = threadIdx.x;
    const int m   = sb * TPB + tid;

    float v = __builtin_huge_valf();
#pragma unroll
    for (int s = 0; s < S_SPLIT; ++s)
        v = fminf(v, g_ws[((size_t)(b * S_SPLIT + s)) * KPTS + m]);

#pragma unroll
    for (int off = 32; off; off >>= 1)
        v = fmaxf(v, __shfl_down(v, off, 64));

    __shared__ float red[TPB / 64];
    if ((tid & 63) == 0) red[tid >> 6] = v;
    __syncthreads();
    if (tid == 0)
        g_partial[blk] = fmaxf(fmaxf(red[0], red[1]), fmaxf(red[2], red[3]));
}

// ---- phaseC: single wave -> weighted mean, single writer ------------------
__global__ void phaseC(const float* __restrict__ w, float* __restrict__ out) {
    const int tid = threadIdx.x;             // 64 threads
    float v = 0.0f;
    if (tid < BATCH) {
        float mx = -__builtin_huge_valf();
#pragma unroll
        for (int i = 0; i < SB; ++i)
            mx = fmaxf(mx, g_partial[tid * SB + i]);
        v = mx * w[tid] * (1.0f / BATCH);
    }
#pragma unroll
    for (int off = 4; off; off >>= 1)        // sum lanes 0..7
        v += __shfl_down(v, off, 64);
    if (tid == 0) out[0] = v;
}

extern "C" void kernel_launch(void* const* d_in, const int* in_sizes, int n_in,
                              void* d_out, int out_size, void* d_ws, size_t ws_size,
                              hipStream_t stream) {
    const float* adv = (const float*)d_in[0];   // [B, K, 3]
    const float* ori = (const float*)d_in[1];   // [B, K, 3]
    const float* w   = (const float*)d_in[2];   // [B]
    float* out = (float*)d_out;
    (void)d_ws; (void)ws_size;

    phaseA<<<GRID_A, TPB, 0, stream>>>(adv, ori);
    phaseB<<<GRID_B, TPB, 0, stream>>>();
    phaseC<<<1, 64, 0, stream>>>(w, out);
}